// Round 7
// baseline (626.880 us; speedup 1.0000x reference)
//
#include <hip/hip_runtime.h>
#include <cstdint>
#include <cstddef>

// ============================================================================
// LSTMCellQ. Round 12: r11 merge with the block-decomposition bug FIXED.
//  - r11 bug: mfma family used col0=(mb&31)*64 / row0=(mb>>5)*128 -> cols
//    2048..4095 never written, rows 4096..8191 OOB (corrupted bm). Correct
//    decomposition is 64 col-blocks x 32 row-blocks: col0=(mb&63)*64,
//    row0=(mb>>6)*128 (matches r10's dim3(64,32) grid).
//  - everything else identical to r11: merged dispatch (even=mfma, odd=p0),
//    disjoint outputs (p0 -> 2MB bitmap, mfma -> pure byte store), tail ORs
//    bit 3 back; r10-verified launch fusion + tail LDS tables.
// Round-5 lattice analysis unchanged: only ih plane-0 bit-exact (p0 f32);
// hh m=0..3 + ih m=1..3 via i16-grid (1/6144) hi/lo i8 MFMA, integer combine.
// RNG (verified): threefry partitionable, foldlike split, bits=x0^x1,
// CHLO Giles erfinv f32, device logf, rintf round-half-even.
// ============================================================================

typedef int v4i __attribute__((ext_vector_type(4)));

struct KPc { uint32_t a, b; };

__host__ __device__ constexpr KPc ctf(uint32_t k0, uint32_t k1v, uint32_t c0, uint32_t c1) {
  uint32_t ks2 = k0 ^ k1v ^ 0x1BD11BDAu;
  uint32_t x0 = c0 + k0;
  uint32_t x1 = c1 + k1v;
  uint32_t r0[4] = {13u, 15u, 26u, 6u};
  uint32_t r1[4] = {17u, 29u, 16u, 24u};
  uint32_t ks[3] = {k0, k1v, ks2};
  for (int g = 0; g < 5; ++g) {
    for (int j = 0; j < 4; ++j) {
      uint32_t rr = (g & 1) ? r1[j] : r0[j];
      x0 += x1;
      x1 = (x1 << rr) | (x1 >> (32u - rr));
      x1 ^= x0;
    }
    x0 += ks[(g + 1) % 3];
    x1 += ks[(g + 2) % 3] + (uint32_t)(g + 1);
  }
  return KPc{x0, x1};
}

constexpr KPc K1K  = ctf(0u, 42u, 0u, 0u);
constexpr KPc K2K  = ctf(0u, 42u, 0u, 1u);
constexpr KPc KWIH = ctf(K1K.a, K1K.b, 0u, 0u);
constexpr KPc KBIH = ctf(K1K.a, K1K.b, 0u, 1u);
constexpr KPc KWHH = ctf(K2K.a, K2K.b, 0u, 0u);
constexpr KPc KBHH = ctf(K2K.a, K2K.b, 0u, 1u);

__device__ __forceinline__ uint32_t tf_bits(uint32_t k0, uint32_t k1v, uint32_t j) {
  KPc r = ctf(k0, k1v, 0u, j);
  return r.a ^ r.b;
}

// ---------------- float max-reduction with order-encoded uint ----------------
__device__ __forceinline__ unsigned encf(float f) {
  unsigned u = __float_as_uint(f);
  return (u & 0x80000000u) ? ~u : (u | 0x80000000u);
}
__device__ __forceinline__ float decf(unsigned e) {
  unsigned u = (e & 0x80000000u) ? (e & 0x7FFFFFFFu) : ~e;
  return __uint_as_float(u);
}

__device__ __forceinline__ void rmax_seg(const float* __restrict__ x, int n,
                                         unsigned* __restrict__ out, int rbid, int nblk) {
  unsigned best = 0u;
  for (int i = rbid * 256 + threadIdx.x; i < n; i += nblk * 256) {
    unsigned e = encf(x[i]);
    best = best > e ? best : e;
  }
  for (int off = 32; off > 0; off >>= 1) {
    unsigned o = __shfl_down(best, off, 64);
    best = best > o ? best : o;
  }
  __shared__ unsigned sm[4];
  int lane = threadIdx.x & 63, wv = threadIdx.x >> 6;
  if (lane == 0) sm[wv] = best;
  __syncthreads();
  if (threadIdx.x == 0) {
    unsigned b = sm[0];
    for (int i = 1; i < 4; ++i) b = b > sm[i] ? b : sm[i];
    atomicMax(out, b);
  }
}

__global__ void rmax_all_kernel(const float* __restrict__ wih, const float* __restrict__ whh,
                                const float* __restrict__ bih, const float* __restrict__ bhh,
                                unsigned* __restrict__ enc) {
  int b = blockIdx.x;
  if (b < 512)       rmax_seg(wih, 4 * 256 * 4096,  enc + 0, b,        512);
  else if (b < 1024) rmax_seg(whh, 4 * 1024 * 4096, enc + 1, b - 512,  512);
  else if (b < 1088) rmax_seg(bih, 16384,           enc + 2, b - 1024, 64);
  else               rmax_seg(bhh, 16384,           enc + 3, b - 1088, 64);
}

// ---------------- XLA-replicated erfinv / uniform->normal ----------------
__device__ __forceinline__ float xla_log1p(float t) {
  float small = __fmul_rn(__fadd_rn(__fmul_rn(-0.5f, t), 1.0f), t);
  float large = logf(__fadd_rn(t, 1.0f));
  return (fabsf(t) < 1e-4f) ? small : large;
}

__device__ __forceinline__ float xla_erfinv(float x) {
  float w = -xla_log1p(-__fmul_rn(x, x));
  float p;
  if (w < 5.0f) {
    float ww = __fadd_rn(w, -2.5f);
    p = 2.81022636e-08f;
    p = __fadd_rn(3.43273939e-07f, __fmul_rn(p, ww));
    p = __fadd_rn(-3.5233877e-06f, __fmul_rn(p, ww));
    p = __fadd_rn(-4.39150654e-06f, __fmul_rn(p, ww));
    p = __fadd_rn(0.00021858087f, __fmul_rn(p, ww));
    p = __fadd_rn(-0.00125372503f, __fmul_rn(p, ww));
    p = __fadd_rn(-0.00417768164f, __fmul_rn(p, ww));
    p = __fadd_rn(0.246640727f, __fmul_rn(p, ww));
    p = __fadd_rn(1.50140941f, __fmul_rn(p, ww));
  } else {
    float ww = __fadd_rn(sqrtf(w), -3.0f);
    p = -0.000200214257f;
    p = __fadd_rn(0.000100950558f, __fmul_rn(p, ww));
    p = __fadd_rn(0.00134934322f, __fmul_rn(p, ww));
    p = __fadd_rn(-0.00367342844f, __fmul_rn(p, ww));
    p = __fadd_rn(0.00573950773f, __fmul_rn(p, ww));
    p = __fadd_rn(-0.0076224613f, __fmul_rn(p, ww));
    p = __fadd_rn(0.00943887047f, __fmul_rn(p, ww));
    p = __fadd_rn(1.00167406f, __fmul_rn(p, ww));
    p = __fadd_rn(2.83297682f, __fmul_rn(p, ww));
  }
  return __fmul_rn(p, x);
}

__device__ __forceinline__ float normal_from_bits(uint32_t bits) {
  float u01 = __uint_as_float((bits >> 9) | 0x3f800000u) - 1.0f;
  const float lo = -0x1.fffffep-1f;
  float u = fmaxf(lo, __fadd_rn(__fmul_rn(u01, 2.0f), lo));
  return __fmul_rn(0x1.6a09e6p+0f, xla_erfinv(u));
}

__device__ __forceinline__ float quantw(float x) {
  float xs = fminf(fmaxf(x, -0.9921875f), 0.9921875f);
  return __fmul_rn(rintf(__fmul_rn(xs, 128.0f)), 0.0078125f);
}

// ---------------- fused preprocessing (kv/aih/ahh/bias/t0/bt) ----------------
__device__ void do_kv(const float* __restrict__ x, const float* __restrict__ ap,
                      const float* __restrict__ offp, unsigned char* __restrict__ kvT,
                      int Kdim, int bx, int by, unsigned char* sh) {
  unsigned char (*tile)[65] = (unsigned char (*)[65])sh;
  const int tid = threadIdx.x;
  const int bt = bx * 64, it = by * 64;
  const float a = ap[0], off = offp[0];
#pragma unroll
  for (int e = 0; e < 16; ++e) {
    int idx = e * 256 + tid;
    int bl = idx >> 6, il = idx & 63;
    float v = fmaxf(-a, fminf(x[(size_t)(bt + bl) * Kdim + it + il], a));
    float t = __fdiv_rn(__fadd_rn(v, off), __fmul_rn(a, 2.0f));
    int k = (int)rintf(__fmul_rn(15.0f, t));
    tile[il][bl] = (unsigned char)(k & 15);
  }
  __syncthreads();
#pragma unroll
  for (int e = 0; e < 16; ++e) {
    int idx = e * 256 + tid;
    int il = idx >> 6, bl = idx & 63;
    kvT[(size_t)(it + il) * 4096 + bt + bl] = tile[il][bl];
  }
}

__device__ void do_aih(const float* __restrict__ input, const float* __restrict__ a1p,
                       signed char* __restrict__ A, int rbid) {
  int j = rbid * 256 + threadIdx.x;
  if (j >= 4096 * 256) return;
  float a = a1p[0];
  float v = fmaxf(-a, fminf(input[j], a));
  float t = __fdiv_rn(__fadd_rn(v, a), __fmul_rn(a, 2.0f));
  int kq = (int)rintf(__fmul_rn(15.0f, t));
  A[j]                  = (signed char)((kq >> 2) & 1);
  A[1048576 + j]        = (signed char)((kq >> 1) & 1);
  A[2097152 + j]        = (signed char)(kq & 1);
}

__device__ void do_ahh(const float* __restrict__ hx, const float* __restrict__ a11p,
                       const float* __restrict__ a1p, signed char* __restrict__ A, int rbid) {
  int j = rbid * 256 + threadIdx.x;
  if (j >= 4096 * 1024) return;
  float a = a11p[0], off = a1p[0];
  float v = fmaxf(-a, fminf(hx[j], a));
  float t = __fdiv_rn(__fadd_rn(v, off), __fmul_rn(a, 2.0f));
  int kq = (int)rintf(__fmul_rn(15.0f, t));
  A[j]                      = (signed char)((kq >> 3) & 1);
  A[(size_t)(1 << 22) + j]  = (signed char)((kq >> 2) & 1);
  A[(size_t)(2 << 22) + j]  = (signed char)((kq >> 1) & 1);
  A[(size_t)(3 << 22) + j]  = (signed char)(kq & 1);
}

__device__ void do_bias(const float* __restrict__ bsrc, float* __restrict__ bq,
                        float* __restrict__ nb, int n, const unsigned* __restrict__ encp,
                        uint32_t k0, uint32_t k1v, int rbid) {
  int j = rbid * 256 + threadIdx.x;
  if (j >= n) return;
  float bmax = decf(*encp);
  float nrm = normal_from_bits(tf_bits(k0, k1v, (uint32_t)j));
  bq[j] = quantw(bsrc[j]);
  nb[j] = __fmul_rn(__fmul_rn(nrm, bmax), 0.1f);
}

__device__ void do_t0(const float* __restrict__ W, float* __restrict__ T0,
                      const unsigned* __restrict__ encp, int rbid) {
  int j = rbid * 256 + threadIdx.x;
  if (j >= 1048576) return;
  float wmax = decf(*encp);
  float nrm = normal_from_bits(tf_bits(KWIH.a, KWIH.b, (uint32_t)j));
  float nw = __fmul_rn(__fmul_rn(nrm, wmax), 0.1f);
  T0[j] = __fadd_rn(quantw(W[j]), nw);
}

__device__ void do_bt(const float* __restrict__ W, signed char* __restrict__ Bt,
                      const unsigned* __restrict__ encp, int K, int m0, int nPlanes,
                      uint32_t k0k, uint32_t k1k, int bx, int by, int bz,
                      unsigned char* sh) {
  signed char* lhi = (signed char*)sh;
  signed char* llo = (signed char*)sh + 4352;
  const int tid = threadIdx.x;
  const int m = m0 + bz;
  const int kt = by * 64, ct = bx * 64;
  const float wmax = decf(*encp);
#pragma unroll 4
  for (int i = 0; i < 16; ++i) {
    int e = i * 256 + tid;
    int kl = e >> 6, cl = e & 63;
    uint32_t j = (uint32_t)(((m * K + kt + kl) << 12) + ct + cl);
    float nrm = normal_from_bits(tf_bits(k0k, k1k, j));
    float t = __fadd_rn(quantw(W[j]), __fmul_rn(__fmul_rn(nrm, wmax), 0.1f));
    int ti = (int)rintf(__fmul_rn(t, 6144.0f));
    int hi = (ti + 128) >> 8;
    int lo = ti - (hi << 8);
    lhi[cl * 68 + kl] = (signed char)hi;
    llo[cl * 68 + kl] = (signed char)lo;
  }
  __syncthreads();
  const size_t planeElems = (size_t)K << 12;
  signed char* bh = Bt + (size_t)bz * planeElems;
  signed char* bl = Bt + (size_t)(nPlanes + bz) * planeElems;
#pragma unroll 4
  for (int i = 0; i < 16; ++i) {
    int f = i * 256 + tid;
    int cl = f >> 6, kl = f & 63;
    size_t o = (size_t)(ct + cl) * K + kt + kl;
    bh[o] = lhi[cl * 68 + kl];
    bl[o] = llo[cl * 68 + kl];
  }
}

// block ranges: kv[0,256) aih[256,4352) ahh[4352,20736) biasih[20736,20800)
// biashh[20800,20864) t0[20864,24960) bt_hh[24960,29056) bt_ih[29056,29824)
__global__ __launch_bounds__(256) void prep_all_kernel(
    const float* __restrict__ input, const float* __restrict__ hx,
    const float* __restrict__ wih, const float* __restrict__ whh,
    const float* __restrict__ bih, const float* __restrict__ bhh,
    const float* __restrict__ a1p, const float* __restrict__ a11p,
    const unsigned* __restrict__ enc,
    unsigned char* __restrict__ kvT, signed char* __restrict__ A_ih,
    signed char* __restrict__ A_hh, float* __restrict__ bq_ih, float* __restrict__ nb_ih,
    float* __restrict__ bq_hh, float* __restrict__ nb_hh, float* __restrict__ T0,
    signed char* __restrict__ Bt_hh, signed char* __restrict__ Bt_ih) {
  __shared__ __align__(16) unsigned char sh[8704];
  int b = blockIdx.x;
  if (b < 256) {
    do_kv(input, a1p, a1p, kvT, 256, b & 63, b >> 6, sh);
  } else if (b < 4352) {
    do_aih(input, a1p, A_ih, b - 256);
  } else if (b < 20736) {
    do_ahh(hx, a11p, a1p, A_hh, b - 4352);
  } else if (b < 20800) {
    do_bias(bih, bq_ih, nb_ih, 16384, enc + 2, KBIH.a, KBIH.b, b - 20736);
  } else if (b < 20864) {
    do_bias(bhh, bq_hh, nb_hh, 16384, enc + 3, KBHH.a, KBHH.b, b - 20800);
  } else if (b < 24960) {
    do_t0(wih, T0, enc + 0, b - 20864);
  } else if (b < 29056) {
    int t = b - 24960;
    do_bt(whh, Bt_hh, enc + 1, 1024, 0, 4, KWHH.a, KWHH.b, t & 63, (t >> 6) & 15, t >> 10, sh);
  } else {
    int t = b - 29056;
    do_bt(wih, Bt_ih, enc + 0, 256, 1, 3, KWIH.a, KWIH.b, t & 63, (t >> 6) & 3, t >> 8, sh);
  }
}

// ---------------- merged GEMM dispatch: mfma blocks (even) + p0 blocks (odd) -
// p0 family: bit-exact f32, global-broadcast t feed (r7-measured code path).
// Writes 1 bit/elem into bm (one u32 store/thread; no atomics, no races).
// mfma family: r7 structure (measured 193us), epilogue is a PURE STORE into
// Kp (each byte owned by exactly one thread; bit 3 merged in tail).
// Decomposition (FIXED): mb in 0..2047 -> col0=(mb&63)*64 (64 col-blocks),
// row0=(mb>>6)*128 (32 row-blocks) == r10's dim3(64,32).
typedef __attribute__((address_space(3))) signed char lds_i8;
typedef __attribute__((address_space(1))) const signed char g_i8;

__device__ __forceinline__ void glds16(const signed char* g, signed char* l) {
  __builtin_amdgcn_global_load_lds((g_i8*)g, (lds_i8*)l, 16, 0, 0);
}

__global__ __launch_bounds__(256, 3) void gemm_mega_kernel(
    const signed char* __restrict__ Ahh, const signed char* __restrict__ Bthh,
    const signed char* __restrict__ Aih, const signed char* __restrict__ Btih,
    const float* __restrict__ bqh, const float* __restrict__ nbh,
    const float* __restrict__ bqi, const float* __restrict__ nbi,
    const float* __restrict__ T0, const unsigned char* __restrict__ kvT,
    unsigned char* __restrict__ Kp, unsigned* __restrict__ bm) {
  // [buf][ A:128x64 | H:64x64 | L:64x64 ] bytes, triple-buffered (mfma family)
  __shared__ __align__(16) signed char smbuf[3][16384];
  const int HOFF = 8192, LOFF = 12288;

  const int tid = threadIdx.x;
  const int lane = tid & 63, wv = tid >> 6;

  if (blockIdx.x & 1) {
    // ------------------ p0 family (odd blocks) ------------------
    const int p = blockIdx.x >> 1;           // 0..2047
    const int c0 = (p & 127) * 32;
    const int row = (p >> 7) * 256 + wv * 64 + lane;

    float acc[32];
#pragma unroll
    for (int j = 0; j < 32; ++j) acc[j] = 0.0f;

    const unsigned char* kvp = kvT + row;
#pragma unroll 2
    for (int k = 0; k < 256; ++k) {
      unsigned nib = kvp[(size_t)k << 12];
      float f = (float)((nib >> 3) & 1u);
      const float4* tp = (const float4*)(T0 + ((size_t)k << 12) + c0);
      float4 tv[8];
#pragma unroll
      for (int q = 0; q < 8; ++q) tv[q] = tp[q];
#pragma unroll
      for (int q = 0; q < 8; ++q) {
        acc[q * 4 + 0] = __builtin_fmaf(f, tv[q].x, acc[q * 4 + 0]);
        acc[q * 4 + 1] = __builtin_fmaf(f, tv[q].y, acc[q * 4 + 1]);
        acc[q * 4 + 2] = __builtin_fmaf(f, tv[q].z, acc[q * 4 + 2]);
        acc[q * 4 + 3] = __builtin_fmaf(f, tv[q].w, acc[q * 4 + 3]);
      }
    }

    unsigned word = 0u;
#pragma unroll
    for (int j = 0; j < 32; ++j) {
      int col = c0 + j;
      float s = __fadd_rn(__fadd_rn(acc[j], bqi[col]), nbi[col]);
      if (s > 0.5f) word |= (1u << j);
    }
    bm[(size_t)row * 128 + (c0 >> 5)] = word;
    return;
  }

  // ------------------ mfma family (even blocks) ------------------
  const int mb = blockIdx.x >> 1;            // 0..2047
  const int col0 = (mb & 63) * 64;           // 64 col-blocks (FIXED)
  const int row0 = (mb >> 6) * 128;          // 32 row-blocks (FIXED)
  const int wrow = (wv >> 1) * 64;   // 0 / 64
  const int wcol = (wv & 1) * 32;    // 0 / 32

  const int l15 = lane & 15;
  const int cc  = (((lane >> 4) ^ ((lane >> 1) & 3)) << 4);        // frag-read chunk byte
  const int xq  = ((((lane & 3) ^ ((lane >> 3) & 3))) << 4);       // stage source chunk byte
  const int lr  = lane >> 2;                                       // stage local row 0..15

  uint32_t k12[4][2];
#pragma unroll
  for (int rf = 0; rf < 4; ++rf) { k12[rf][0] = 0u; k12[rf][1] = 0u; }

  for (int sub = 0; sub < 7; ++sub) {
    int K, w;
    const signed char *A, *Bh, *Bl;
    const float *bqp, *nbp;
    if (sub < 4) {                       // hh plane m = sub
      int m = sub;
      K = 1024;
      A  = Ahh  + ((size_t)m << 22);
      Bh = Bthh + ((size_t)m << 22);
      Bl = Bthh + ((size_t)(4 + m) << 22);
      bqp = bqh + (m << 12); nbp = nbh + (m << 12);
      w = (1 << (3 - m)) << 4;
    } else {                             // ih plane m = sub-3 (1..3)
      int m = sub - 3;
      K = 256;
      A  = Aih  + ((size_t)(m - 1) << 20);
      Bh = Btih + ((size_t)(m - 1) << 20);
      Bl = Btih + ((size_t)(3 + m - 1) << 20);
      bqp = bqi + (m << 12); nbp = nbi + (m << 12);
      w = 1 << (3 - m);
    }

    // per-lane pre-swizzled source pointers (row base mult of 16 -> the
    // (row>>1)&3 swizzle reduces to (l>>3)&3, identical for all 4 calls)
    const size_t soff = (size_t)lr * K + xq;
    const signed char* gA  = A  + (size_t)(row0 + 32 * wv) * K + soff;
    const signed char* gA2 = gA + (size_t)16 * K;
    const signed char* gH  = Bh + (size_t)(col0 + 16 * wv) * K + soff;
    const signed char* gL  = Bl + (size_t)(col0 + 16 * wv) * K + soff;

    auto stage = [&](signed char* base, int k0) {
      glds16(gA  + k0, base + (32 * wv) * 64);
      glds16(gA2 + k0, base + (32 * wv + 16) * 64);
      glds16(gH  + k0, base + HOFF + (16 * wv) * 64);
      glds16(gL  + k0, base + LOFF + (16 * wv) * 64);
    };

    v4i ach[4][2], acl[4][2];
    v4i zero = {0, 0, 0, 0};
#pragma unroll
    for (int rf = 0; rf < 4; ++rf)
#pragma unroll
      for (int cf = 0; cf < 2; ++cf) { ach[rf][cf] = zero; acl[rf][cf] = zero; }

    signed char* bc = &smbuf[0][0];      // current (tile t)
    signed char* bn = &smbuf[1][0];      // next (tile t+1)
    signed char* bf = &smbuf[2][0];      // free (target for tile t+2)

    const int nt = K >> 6;
    stage(bc, 0);
    stage(bn, 64);

    for (int t = 0; t < nt; ++t) {
      if (t + 1 < nt) {
        asm volatile("s_waitcnt vmcnt(4)" ::: "memory");   // tile t done, t+1 flies
      } else {
        asm volatile("s_waitcnt vmcnt(0)" ::: "memory");   // last tile: full drain
      }
      __builtin_amdgcn_s_barrier();
      __builtin_amdgcn_sched_barrier(0);
      if (t + 2 < nt) stage(bf, (t + 2) << 6);             // newest 4, fly across barriers

      v4i af[4], bfh[2], bfl[2];
#pragma unroll
      for (int rf = 0; rf < 4; ++rf)
        af[rf] = *(const v4i*)(bc + (wrow + rf * 16 + l15) * 64 + cc);
#pragma unroll
      for (int cf = 0; cf < 2; ++cf) {
        bfh[cf] = *(const v4i*)(bc + HOFF + (wcol + cf * 16 + l15) * 64 + cc);
        bfl[cf] = *(const v4i*)(bc + LOFF + (wcol + cf * 16 + l15) * 64 + cc);
      }
#pragma unroll
      for (int rf = 0; rf < 4; ++rf)
#pragma unroll
        for (int cf = 0; cf < 2; ++cf) {
          ach[rf][cf] = __builtin_amdgcn_mfma_i32_16x16x64_i8(af[rf], bfh[cf], ach[rf][cf], 0, 0, 0);
          acl[rf][cf] = __builtin_amdgcn_mfma_i32_16x16x64_i8(af[rf], bfl[cf], acl[rf][cf], 0, 0, 0);
        }
      signed char* tmp = bc; bc = bn; bn = bf; bf = tmp;   // rotate buffers
    }
    __syncthreads();                     // sub boundary: reads done, safe restage

    // epilogue: float math bit-identical to round 5; pack decision bits per r
#pragma unroll
    for (int cf = 0; cf < 2; ++cf) {
      int col = col0 + wcol + cf * 16 + l15;
      float bqc = bqp[col];
      float nbc = nbp[col];
#pragma unroll
      for (int rf = 0; rf < 4; ++rf)
#pragma unroll
        for (int r = 0; r < 4; ++r) {
          int tot = ach[rf][cf][r] * 256 + acl[rf][cf][r];
          float s = __fmul_rn((float)tot, (1.0f / 6144.0f));
          float s2 = __fadd_rn(__fadd_rn(s, bqc), nbc);
          if (s2 > 0.5f) k12[rf][cf] += ((uint32_t)w << (8 * r));
        }
    }
  }

  // pure store (each byte owned by exactly one thread; bit 3 merged in tail)
#pragma unroll
  for (int rf = 0; rf < 4; ++rf)
#pragma unroll
    for (int cf = 0; cf < 2; ++cf)
#pragma unroll
      for (int r = 0; r < 4; ++r) {
        int row = row0 + wrow + rf * 16 + ((lane >> 4) << 2) + r;
        int col = col0 + wcol + cf * 16 + l15;
        Kp[((size_t)row << 12) + col] = (unsigned char)((k12[rf][cf] >> (8 * r)) & 255u);
      }
}

// ---------------- elementwise tail: LDS tables for all transcendentals ------
// gate() inputs take only 256 lattice values; nc only 255 quantized values.
// Tables computed per-block with the EXACT double expressions of round 5
// -> bit-identical outputs. Grid-stride 2048 blocks amortizes table cost.
// pk = Kp byte (bits 0-2,4-7 from mfma) | plane-0 bit from bitmap << 3.
__device__ __forceinline__ float quant8(float x, float r) {
  float xs = __fdiv_rn(x, r);
  xs = fminf(fmaxf(xs, -0.9921875f), 0.9921875f);
  float q = rintf(__fmul_rn(xs, 128.0f));
  return __fmul_rn(__fdiv_rn(q, 128.0f), r);
}
__device__ __forceinline__ float pactf(float x, float a) { return fminf(fmaxf(x, -a), a); }
__device__ __forceinline__ double sigd(double x) { return 1.0 / (1.0 + exp(-x)); }

__global__ __launch_bounds__(256) void tail_kernel(
    const unsigned char* __restrict__ Kp, const unsigned char* __restrict__ bmb,
    const float* __restrict__ cx,
    const float* a1p, const float* a3p, const float* a4p,
    const float* a5p, const float* a6p, const float* a7p,
    const float* a8p, const float* a9p, const float* a10p,
    const float* a11p, float* __restrict__ out) {
  __shared__ float Tf[256], Ti[256], Tj[256], To[256], Tac[256];
  const int tid = threadIdx.x;
  const double a1 = (double)a1p[0], a11 = (double)a11p[0];
  const float a3 = a3p[0], a4 = a4p[0], a5 = a5p[0], a6 = a6p[0];
  const float a7 = a7p[0], a8 = a8p[0], a9 = a9p[0], a10 = a10p[0], a11f = a11p[0];

  {
    int pk = tid;
    double s1 = (double)(pk & 15) * (1.0 / 15.0);
    double s2 = (double)(pk >> 4) * (1.0 / 15.0);
    double g = (s1 * (2.0 * a1) - a1) + (s2 * (2.0 * a11) - a11);
    Tf[pk] = quant8(pactf((float)sigd(g), a3), a3);
    Ti[pk] = quant8(pactf((float)sigd(g), a4), a4);
    Tj[pk] = quant8(pactf((float)tanh(g), a5), a5);
    To[pk] = quant8(pactf((float)sigd(g), a6), a6);
    if (tid < 255) {
      float qf = (float)(tid - 127);                       // q in [-127,127]
      float ncv = __fmul_rn(__fdiv_rn(qf, 128.0f), a9);
      Tac[tid] = quant8(pactf((float)tanh((double)ncv), a10), a10);
    }
  }
  __syncthreads();

  for (int idx = blockIdx.x * 256 + tid; idx < 4194304; idx += 2048 * 256) {
    int b = idx >> 10, h = idx & 1023;
    const unsigned char* row = Kp + (size_t)b * 4096 + h;
    int base = b * 512 + (h >> 3);
    int sh3 = h & 7;
    int pI = row[0]    | (((bmb[base]       >> sh3) & 1) << 3);
    int pJ = row[1024] | (((bmb[base + 128] >> sh3) & 1) << 3);
    int pF = row[2048] | (((bmb[base + 256] >> sh3) & 1) << 3);
    int pO = row[3072] | (((bmb[base + 384] >> sh3) & 1) << 3);
    float fg  = Tf[pF];
    float ig  = Ti[pI];
    float act = Tj[pJ];
    float og  = To[pO];
    float cxv = cx[idx];
    float gc  = quant8(pactf(__fmul_rn(cxv, fg), a7), a7);
    float ai  = quant8(pactf(__fmul_rn(ig, act), a8), a8);
    // nc = quant8(pactf(gc+ai, a9), a9), with integer grid index exposed
    float s   = __fadd_rn(gc, ai);
    float xs  = fminf(fmaxf(__fdiv_rn(pactf(s, a9), a9), -0.9921875f), 0.9921875f);
    float qf  = rintf(__fmul_rn(xs, 128.0f));
    float nc  = __fmul_rn(__fdiv_rn(qf, 128.0f), a9);
    float ac  = Tac[(int)qf + 127];
    float nh  = quant8(pactf(__fmul_rn(ac, og), a11f), a11f);
    out[idx] = nh;
    out[4194304 + idx] = nc;
  }
}

// ============================================================================
extern "C" void kernel_launch(void* const* d_in, const int* in_sizes, int n_in,
                              void* d_out, int out_size, void* d_ws, size_t ws_size,
                              hipStream_t stream) {
  const float* input = (const float*)d_in[0];
  const float* hx    = (const float*)d_in[1];
  const float* cx    = (const float*)d_in[2];
  const float* wih   = (const float*)d_in[3];
  const float* whh   = (const float*)d_in[4];
  const float* bih   = (const float*)d_in[5];
  const float* bhh   = (const float*)d_in[6];
  const float* a1p   = (const float*)d_in[7];
  const float* a3p   = (const float*)d_in[8];
  const float* a4p   = (const float*)d_in[9];
  const float* a5p   = (const float*)d_in[10];
  const float* a6p   = (const float*)d_in[11];
  const float* a7p   = (const float*)d_in[12];
  const float* a8p   = (const float*)d_in[13];
  const float* a9p   = (const float*)d_in[14];
  const float* a10p  = (const float*)d_in[15];
  const float* a11p  = (const float*)d_in[16];

  char* ws = (char*)d_ws;
  unsigned* enc        = (unsigned*)ws;                            // 256 B
  float* T0            = (float*)(ws + 256);                       // 4 MiB  [256][4096]
  float* bq_ih         = (float*)(ws + 256 + 4194304);             // 64 KiB x4
  float* nb_ih         = bq_ih + 16384;
  float* bq_hh         = nb_ih + 16384;
  float* nb_hh         = bq_hh + 16384;
  unsigned char* kv_ih = (unsigned char*)(nb_hh + 16384);          // 1 MiB [256][4096]
  signed char* A_hh    = (signed char*)(kv_ih + 1048576);          // 16 MiB [4][4096][1024]
  signed char* Bt_hh   = A_hh + 16777216;                          // 32 MiB [2][4][4096][1024]
  signed char* A_ih    = Bt_hh + 33554432;                         // 3 MiB [3][4096][256]
  signed char* Bt_ih   = A_ih + 3145728;                           // 6 MiB [2][3][4096][256]
  unsigned char* Kp    = (unsigned char*)(Bt_ih + 6291456);        // 16 MiB
  unsigned* bm         = (unsigned*)(Kp + 16777216);               // 2 MiB [4096][128]
  // total ~80.3 MiB

  hipMemsetAsync(enc, 0, 64, stream);

  rmax_all_kernel<<<1152, 256, 0, stream>>>(wih, whh, bih, bhh, enc);

  prep_all_kernel<<<29824, 256, 0, stream>>>(input, hx, wih, whh, bih, bhh, a1p, a11p,
                                             enc, kv_ih, A_ih, A_hh, bq_ih, nb_ih,
                                             bq_hh, nb_hh, T0, Bt_hh, Bt_ih);

  gemm_mega_kernel<<<4096, 256, 0, stream>>>(A_hh, Bt_hh, A_ih, Bt_ih,
                                             bq_hh, nb_hh, bq_ih, nb_ih,
                                             T0, kv_ih, Kp, bm);

  tail_kernel<<<2048, 256, 0, stream>>>(Kp, (const unsigned char*)bm, cx,
                                        a1p, a3p, a4p, a5p, a6p, a7p, a8p, a9p,
                                        a10p, a11p, (float*)d_out);
}

// Round 8
// 589.765 us; speedup vs baseline: 1.0629x; 1.0629x over previous
//
#include <hip/hip_runtime.h>
#include <cstdint>
#include <cstddef>

// ============================================================================
// LSTMCellQ. Round 13: r10 structure (582us measured) + tail fused into
// gemm_mfma via gate-strip column mapping.
//  - r12 lesson: merging p0+mfma into one dispatch regressed (vmem contention
//    + dead-LDS occupancy loss). Keep separate dispatches.
//  - mfma block now computes cols {c0, c0+1024, c0+2048, c0+3072} x 16 (all 4
//    gates for 128 rows x 16 h-cols): wave w stages B strip w (same 16-row
//    chunk geometry as r10 -> K-loop body byte-identical). Epilogue: gate
//    bytes -> LDS, r10 tables per block, exact r10 tail chain inline.
//    Deletes Kp (16MB wr + 16MB scattered rd), tail dispatch, one gap.
//  - gemm_p0: r10 body, output = 2MB bitmap (bit3 read by fused tail).
// Round-5 lattice analysis unchanged: only ih plane-0 bit-exact (p0 f32);
// hh m=0..3 + ih m=1..3 via i16-grid (1/6144) hi/lo i8 MFMA, integer combine.
// RNG (verified): threefry partitionable, foldlike split, bits=x0^x1,
// CHLO Giles erfinv f32, device logf, rintf round-half-even.
// ============================================================================

typedef int v4i __attribute__((ext_vector_type(4)));

struct KPc { uint32_t a, b; };

__host__ __device__ constexpr KPc ctf(uint32_t k0, uint32_t k1v, uint32_t c0, uint32_t c1) {
  uint32_t ks2 = k0 ^ k1v ^ 0x1BD11BDAu;
  uint32_t x0 = c0 + k0;
  uint32_t x1 = c1 + k1v;
  uint32_t r0[4] = {13u, 15u, 26u, 6u};
  uint32_t r1[4] = {17u, 29u, 16u, 24u};
  uint32_t ks[3] = {k0, k1v, ks2};
  for (int g = 0; g < 5; ++g) {
    for (int j = 0; j < 4; ++j) {
      uint32_t rr = (g & 1) ? r1[j] : r0[j];
      x0 += x1;
      x1 = (x1 << rr) | (x1 >> (32u - rr));
      x1 ^= x0;
    }
    x0 += ks[(g + 1) % 3];
    x1 += ks[(g + 2) % 3] + (uint32_t)(g + 1);
  }
  return KPc{x0, x1};
}

constexpr KPc K1K  = ctf(0u, 42u, 0u, 0u);
constexpr KPc K2K  = ctf(0u, 42u, 0u, 1u);
constexpr KPc KWIH = ctf(K1K.a, K1K.b, 0u, 0u);
constexpr KPc KBIH = ctf(K1K.a, K1K.b, 0u, 1u);
constexpr KPc KWHH = ctf(K2K.a, K2K.b, 0u, 0u);
constexpr KPc KBHH = ctf(K2K.a, K2K.b, 0u, 1u);

__device__ __forceinline__ uint32_t tf_bits(uint32_t k0, uint32_t k1v, uint32_t j) {
  KPc r = ctf(k0, k1v, 0u, j);
  return r.a ^ r.b;
}

// ---------------- float max-reduction with order-encoded uint ----------------
__device__ __forceinline__ unsigned encf(float f) {
  unsigned u = __float_as_uint(f);
  return (u & 0x80000000u) ? ~u : (u | 0x80000000u);
}
__device__ __forceinline__ float decf(unsigned e) {
  unsigned u = (e & 0x80000000u) ? (e & 0x7FFFFFFFu) : ~e;
  return __uint_as_float(u);
}

__device__ __forceinline__ void rmax_seg(const float* __restrict__ x, int n,
                                         unsigned* __restrict__ out, int rbid, int nblk) {
  unsigned best = 0u;
  for (int i = rbid * 256 + threadIdx.x; i < n; i += nblk * 256) {
    unsigned e = encf(x[i]);
    best = best > e ? best : e;
  }
  for (int off = 32; off > 0; off >>= 1) {
    unsigned o = __shfl_down(best, off, 64);
    best = best > o ? best : o;
  }
  __shared__ unsigned sm[4];
  int lane = threadIdx.x & 63, wv = threadIdx.x >> 6;
  if (lane == 0) sm[wv] = best;
  __syncthreads();
  if (threadIdx.x == 0) {
    unsigned b = sm[0];
    for (int i = 1; i < 4; ++i) b = b > sm[i] ? b : sm[i];
    atomicMax(out, b);
  }
}

__global__ void rmax_all_kernel(const float* __restrict__ wih, const float* __restrict__ whh,
                                const float* __restrict__ bih, const float* __restrict__ bhh,
                                unsigned* __restrict__ enc) {
  int b = blockIdx.x;
  if (b < 512)       rmax_seg(wih, 4 * 256 * 4096,  enc + 0, b,        512);
  else if (b < 1024) rmax_seg(whh, 4 * 1024 * 4096, enc + 1, b - 512,  512);
  else if (b < 1088) rmax_seg(bih, 16384,           enc + 2, b - 1024, 64);
  else               rmax_seg(bhh, 16384,           enc + 3, b - 1088, 64);
}

// ---------------- XLA-replicated erfinv / uniform->normal ----------------
__device__ __forceinline__ float xla_log1p(float t) {
  float small = __fmul_rn(__fadd_rn(__fmul_rn(-0.5f, t), 1.0f), t);
  float large = logf(__fadd_rn(t, 1.0f));
  return (fabsf(t) < 1e-4f) ? small : large;
}

__device__ __forceinline__ float xla_erfinv(float x) {
  float w = -xla_log1p(-__fmul_rn(x, x));
  float p;
  if (w < 5.0f) {
    float ww = __fadd_rn(w, -2.5f);
    p = 2.81022636e-08f;
    p = __fadd_rn(3.43273939e-07f, __fmul_rn(p, ww));
    p = __fadd_rn(-3.5233877e-06f, __fmul_rn(p, ww));
    p = __fadd_rn(-4.39150654e-06f, __fmul_rn(p, ww));
    p = __fadd_rn(0.00021858087f, __fmul_rn(p, ww));
    p = __fadd_rn(-0.00125372503f, __fmul_rn(p, ww));
    p = __fadd_rn(-0.00417768164f, __fmul_rn(p, ww));
    p = __fadd_rn(0.246640727f, __fmul_rn(p, ww));
    p = __fadd_rn(1.50140941f, __fmul_rn(p, ww));
  } else {
    float ww = __fadd_rn(sqrtf(w), -3.0f);
    p = -0.000200214257f;
    p = __fadd_rn(0.000100950558f, __fmul_rn(p, ww));
    p = __fadd_rn(0.00134934322f, __fmul_rn(p, ww));
    p = __fadd_rn(-0.00367342844f, __fmul_rn(p, ww));
    p = __fadd_rn(0.00573950773f, __fmul_rn(p, ww));
    p = __fadd_rn(-0.0076224613f, __fmul_rn(p, ww));
    p = __fadd_rn(0.00943887047f, __fmul_rn(p, ww));
    p = __fadd_rn(1.00167406f, __fmul_rn(p, ww));
    p = __fadd_rn(2.83297682f, __fmul_rn(p, ww));
  }
  return __fmul_rn(p, x);
}

__device__ __forceinline__ float normal_from_bits(uint32_t bits) {
  float u01 = __uint_as_float((bits >> 9) | 0x3f800000u) - 1.0f;
  const float lo = -0x1.fffffep-1f;
  float u = fmaxf(lo, __fadd_rn(__fmul_rn(u01, 2.0f), lo));
  return __fmul_rn(0x1.6a09e6p+0f, xla_erfinv(u));
}

__device__ __forceinline__ float quantw(float x) {
  float xs = fminf(fmaxf(x, -0.9921875f), 0.9921875f);
  return __fmul_rn(rintf(__fmul_rn(xs, 128.0f)), 0.0078125f);
}

// ---------------- fused preprocessing (kv/aih/ahh/bias/t0/bt) ----------------
__device__ void do_kv(const float* __restrict__ x, const float* __restrict__ ap,
                      const float* __restrict__ offp, unsigned char* __restrict__ kvT,
                      int Kdim, int bx, int by, unsigned char* sh) {
  unsigned char (*tile)[65] = (unsigned char (*)[65])sh;
  const int tid = threadIdx.x;
  const int bt = bx * 64, it = by * 64;
  const float a = ap[0], off = offp[0];
#pragma unroll
  for (int e = 0; e < 16; ++e) {
    int idx = e * 256 + tid;
    int bl = idx >> 6, il = idx & 63;
    float v = fmaxf(-a, fminf(x[(size_t)(bt + bl) * Kdim + it + il], a));
    float t = __fdiv_rn(__fadd_rn(v, off), __fmul_rn(a, 2.0f));
    int k = (int)rintf(__fmul_rn(15.0f, t));
    tile[il][bl] = (unsigned char)(k & 15);
  }
  __syncthreads();
#pragma unroll
  for (int e = 0; e < 16; ++e) {
    int idx = e * 256 + tid;
    int il = idx >> 6, bl = idx & 63;
    kvT[(size_t)(it + il) * 4096 + bt + bl] = tile[il][bl];
  }
}

__device__ void do_aih(const float* __restrict__ input, const float* __restrict__ a1p,
                       signed char* __restrict__ A, int rbid) {
  int j = rbid * 256 + threadIdx.x;
  if (j >= 4096 * 256) return;
  float a = a1p[0];
  float v = fmaxf(-a, fminf(input[j], a));
  float t = __fdiv_rn(__fadd_rn(v, a), __fmul_rn(a, 2.0f));
  int kq = (int)rintf(__fmul_rn(15.0f, t));
  A[j]                  = (signed char)((kq >> 2) & 1);
  A[1048576 + j]        = (signed char)((kq >> 1) & 1);
  A[2097152 + j]        = (signed char)(kq & 1);
}

__device__ void do_ahh(const float* __restrict__ hx, const float* __restrict__ a11p,
                       const float* __restrict__ a1p, signed char* __restrict__ A, int rbid) {
  int j = rbid * 256 + threadIdx.x;
  if (j >= 4096 * 1024) return;
  float a = a11p[0], off = a1p[0];
  float v = fmaxf(-a, fminf(hx[j], a));
  float t = __fdiv_rn(__fadd_rn(v, off), __fmul_rn(a, 2.0f));
  int kq = (int)rintf(__fmul_rn(15.0f, t));
  A[j]                      = (signed char)((kq >> 3) & 1);
  A[(size_t)(1 << 22) + j]  = (signed char)((kq >> 2) & 1);
  A[(size_t)(2 << 22) + j]  = (signed char)((kq >> 1) & 1);
  A[(size_t)(3 << 22) + j]  = (signed char)(kq & 1);
}

__device__ void do_bias(const float* __restrict__ bsrc, float* __restrict__ bq,
                        float* __restrict__ nb, int n, const unsigned* __restrict__ encp,
                        uint32_t k0, uint32_t k1v, int rbid) {
  int j = rbid * 256 + threadIdx.x;
  if (j >= n) return;
  float bmax = decf(*encp);
  float nrm = normal_from_bits(tf_bits(k0, k1v, (uint32_t)j));
  bq[j] = quantw(bsrc[j]);
  nb[j] = __fmul_rn(__fmul_rn(nrm, bmax), 0.1f);
}

__device__ void do_t0(const float* __restrict__ W, float* __restrict__ T0,
                      const unsigned* __restrict__ encp, int rbid) {
  int j = rbid * 256 + threadIdx.x;
  if (j >= 1048576) return;
  float wmax = decf(*encp);
  float nrm = normal_from_bits(tf_bits(KWIH.a, KWIH.b, (uint32_t)j));
  float nw = __fmul_rn(__fmul_rn(nrm, wmax), 0.1f);
  T0[j] = __fadd_rn(quantw(W[j]), nw);
}

__device__ void do_bt(const float* __restrict__ W, signed char* __restrict__ Bt,
                      const unsigned* __restrict__ encp, int K, int m0, int nPlanes,
                      uint32_t k0k, uint32_t k1k, int bx, int by, int bz,
                      unsigned char* sh) {
  signed char* lhi = (signed char*)sh;
  signed char* llo = (signed char*)sh + 4352;
  const int tid = threadIdx.x;
  const int m = m0 + bz;
  const int kt = by * 64, ct = bx * 64;
  const float wmax = decf(*encp);
#pragma unroll 4
  for (int i = 0; i < 16; ++i) {
    int e = i * 256 + tid;
    int kl = e >> 6, cl = e & 63;
    uint32_t j = (uint32_t)(((m * K + kt + kl) << 12) + ct + cl);
    float nrm = normal_from_bits(tf_bits(k0k, k1k, j));
    float t = __fadd_rn(quantw(W[j]), __fmul_rn(__fmul_rn(nrm, wmax), 0.1f));
    int ti = (int)rintf(__fmul_rn(t, 6144.0f));
    int hi = (ti + 128) >> 8;
    int lo = ti - (hi << 8);
    lhi[cl * 68 + kl] = (signed char)hi;
    llo[cl * 68 + kl] = (signed char)lo;
  }
  __syncthreads();
  const size_t planeElems = (size_t)K << 12;
  signed char* bh = Bt + (size_t)bz * planeElems;
  signed char* bl = Bt + (size_t)(nPlanes + bz) * planeElems;
#pragma unroll 4
  for (int i = 0; i < 16; ++i) {
    int f = i * 256 + tid;
    int cl = f >> 6, kl = f & 63;
    size_t o = (size_t)(ct + cl) * K + kt + kl;
    bh[o] = lhi[cl * 68 + kl];
    bl[o] = llo[cl * 68 + kl];
  }
}

// block ranges: kv[0,256) aih[256,4352) ahh[4352,20736) biasih[20736,20800)
// biashh[20800,20864) t0[20864,24960) bt_hh[24960,29056) bt_ih[29056,29824)
__global__ __launch_bounds__(256) void prep_all_kernel(
    const float* __restrict__ input, const float* __restrict__ hx,
    const float* __restrict__ wih, const float* __restrict__ whh,
    const float* __restrict__ bih, const float* __restrict__ bhh,
    const float* __restrict__ a1p, const float* __restrict__ a11p,
    const unsigned* __restrict__ enc,
    unsigned char* __restrict__ kvT, signed char* __restrict__ A_ih,
    signed char* __restrict__ A_hh, float* __restrict__ bq_ih, float* __restrict__ nb_ih,
    float* __restrict__ bq_hh, float* __restrict__ nb_hh, float* __restrict__ T0,
    signed char* __restrict__ Bt_hh, signed char* __restrict__ Bt_ih) {
  __shared__ __align__(16) unsigned char sh[8704];
  int b = blockIdx.x;
  if (b < 256) {
    do_kv(input, a1p, a1p, kvT, 256, b & 63, b >> 6, sh);
  } else if (b < 4352) {
    do_aih(input, a1p, A_ih, b - 256);
  } else if (b < 20736) {
    do_ahh(hx, a11p, a1p, A_hh, b - 4352);
  } else if (b < 20800) {
    do_bias(bih, bq_ih, nb_ih, 16384, enc + 2, KBIH.a, KBIH.b, b - 20736);
  } else if (b < 20864) {
    do_bias(bhh, bq_hh, nb_hh, 16384, enc + 3, KBHH.a, KBHH.b, b - 20800);
  } else if (b < 24960) {
    do_t0(wih, T0, enc + 0, b - 20864);
  } else if (b < 29056) {
    int t = b - 24960;
    do_bt(whh, Bt_hh, enc + 1, 1024, 0, 4, KWHH.a, KWHH.b, t & 63, (t >> 6) & 15, t >> 10, sh);
  } else {
    int t = b - 29056;
    do_bt(wih, Bt_ih, enc + 0, 256, 1, 3, KWIH.a, KWIH.b, t & 63, (t >> 6) & 3, t >> 8, sh);
  }
}

// ---------------- ih plane-0 GEMM: bit-exact f32, global-broadcast t feed ----
// r10 body; output = plane-0 decision bitmap (1 bit/elem, one u32/thread).
__global__ __launch_bounds__(256) void gemm_p0_kernel(
    const float* __restrict__ T0, const float* __restrict__ bq, const float* __restrict__ nb,
    const unsigned char* __restrict__ kvT, unsigned* __restrict__ bm) {
  const int tid = threadIdx.x, lane = tid & 63, wv = tid >> 6;
  const int c0 = blockIdx.x * 32;
  const int row = blockIdx.y * 256 + wv * 64 + lane;

  float acc[32];
#pragma unroll
  for (int j = 0; j < 32; ++j) acc[j] = 0.0f;

  const unsigned char* kvp = kvT + row;
#pragma unroll 2
  for (int k = 0; k < 256; ++k) {
    unsigned nib = kvp[(size_t)k << 12];
    float f = (float)((nib >> 3) & 1u);
    const float4* tp = (const float4*)(T0 + ((size_t)k << 12) + c0);
    float4 tv[8];
#pragma unroll
    for (int q = 0; q < 8; ++q) tv[q] = tp[q];
#pragma unroll
    for (int q = 0; q < 8; ++q) {
      acc[q * 4 + 0] = __builtin_fmaf(f, tv[q].x, acc[q * 4 + 0]);
      acc[q * 4 + 1] = __builtin_fmaf(f, tv[q].y, acc[q * 4 + 1]);
      acc[q * 4 + 2] = __builtin_fmaf(f, tv[q].z, acc[q * 4 + 2]);
      acc[q * 4 + 3] = __builtin_fmaf(f, tv[q].w, acc[q * 4 + 3]);
    }
  }

  unsigned word = 0u;
#pragma unroll
  for (int j = 0; j < 32; ++j) {
    int col = c0 + j;
    float s = __fadd_rn(__fadd_rn(acc[j], bq[col]), nb[col]);
    if (s > 0.5f) word |= (1u << j);
  }
  bm[(size_t)row * 128 + (c0 >> 5)] = word;
}

// ---------------- i8 MFMA GEMM + fused tail -----------------------------
// r7-measured K-loop (193us), gate-strip column mapping: block covers cols
// {c0, c0+1024, c0+2048, c0+3072} x 16 (c0 = bx*16) = all 4 gates for
// 128 rows x 16 h-cols. Wave w stages B strip w (same 16-row chunk geometry
// as r10 -> staging/frag/swizzle code identical, only source base changes).
// Epilogue: gate bytes -> LDS, r10 LDS tables, exact r10 tail chain inline.
__device__ __forceinline__ float quant8(float x, float r) {
  float xs = __fdiv_rn(x, r);
  xs = fminf(fmaxf(xs, -0.9921875f), 0.9921875f);
  float q = rintf(__fmul_rn(xs, 128.0f));
  return __fmul_rn(__fdiv_rn(q, 128.0f), r);
}
__device__ __forceinline__ float pactf(float x, float a) { return fminf(fmaxf(x, -a), a); }
__device__ __forceinline__ double sigd(double x) { return 1.0 / (1.0 + exp(-x)); }

typedef __attribute__((address_space(3))) signed char lds_i8;
typedef __attribute__((address_space(1))) const signed char g_i8;

__device__ __forceinline__ void glds16(const signed char* g, signed char* l) {
  __builtin_amdgcn_global_load_lds((g_i8*)g, (lds_i8*)l, 16, 0, 0);
}

__global__ __launch_bounds__(256, 3) void gemm_mfma_tail_kernel(
    const signed char* __restrict__ Ahh, const signed char* __restrict__ Bthh,
    const signed char* __restrict__ Aih, const signed char* __restrict__ Btih,
    const float* __restrict__ bqh, const float* __restrict__ nbh,
    const float* __restrict__ bqi, const float* __restrict__ nbi,
    const unsigned char* __restrict__ bmb, const float* __restrict__ cx,
    const float* a1p, const float* a3p, const float* a4p,
    const float* a5p, const float* a6p, const float* a7p,
    const float* a8p, const float* a9p, const float* a10p,
    const float* a11p, float* __restrict__ out) {
  const int tid = threadIdx.x;
  const int lane = tid & 63, wv = tid >> 6;
  const int c0 = blockIdx.x * 16;      // h-column base (0..1008)
  const int row0 = blockIdx.y * 128;
  const int wrow = (wv >> 1) * 64;   // 0 / 64
  const int wcol = (wv & 1) * 32;    // 0 / 32

  // [buf][ A:128x64 | H:64x64 | L:64x64 ] bytes, triple-buffered
  __shared__ __align__(16) signed char smbuf[3][16384];
  const int HOFF = 8192, LOFF = 12288;

  const int l15 = lane & 15;
  const int cc  = (((lane >> 4) ^ ((lane >> 1) & 3)) << 4);        // frag-read chunk byte
  const int xq  = ((((lane & 3) ^ ((lane >> 3) & 3))) << 4);       // stage source chunk byte
  const int lr  = lane >> 2;                                       // stage local row 0..15

  uint32_t k12[4][2];
#pragma unroll
  for (int rf = 0; rf < 4; ++rf) { k12[rf][0] = 0u; k12[rf][1] = 0u; }

  for (int sub = 0; sub < 7; ++sub) {
    int K, w;
    const signed char *A, *Bh, *Bl;
    const float *bqp, *nbp;
    if (sub < 4) {                       // hh plane m = sub
      int m = sub;
      K = 1024;
      A  = Ahh  + ((size_t)m << 22);
      Bh = Bthh + ((size_t)m << 22);
      Bl = Bthh + ((size_t)(4 + m) << 22);
      bqp = bqh + (m << 12); nbp = nbh + (m << 12);
      w = (1 << (3 - m)) << 4;
    } else {                             // ih plane m = sub-3 (1..3)
      int m = sub - 3;
      K = 256;
      A  = Aih  + ((size_t)(m - 1) << 20);
      Bh = Btih + ((size_t)(m - 1) << 20);
      Bl = Btih + ((size_t)(3 + m - 1) << 20);
      bqp = bqi + (m << 12); nbp = nbi + (m << 12);
      w = 1 << (3 - m);
    }

    // A source: unchanged. B source: wave w stages strip w = rows
    // [c0 + w*1024, +16) (base multiple of 16 -> swizzle reduction holds).
    const size_t soff = (size_t)lr * K + xq;
    const signed char* gA  = A  + (size_t)(row0 + 32 * wv) * K + soff;
    const signed char* gA2 = gA + (size_t)16 * K;
    const signed char* gH  = Bh + (size_t)(c0 + wv * 1024) * K + soff;
    const signed char* gL  = Bl + (size_t)(c0 + wv * 1024) * K + soff;

    auto stage = [&](signed char* base, int k0) {
      glds16(gA  + k0, base + (32 * wv) * 64);
      glds16(gA2 + k0, base + (32 * wv + 16) * 64);
      glds16(gH  + k0, base + HOFF + (16 * wv) * 64);
      glds16(gL  + k0, base + LOFF + (16 * wv) * 64);
    };

    v4i ach[4][2], acl[4][2];
    v4i zero = {0, 0, 0, 0};
#pragma unroll
    for (int rf = 0; rf < 4; ++rf)
#pragma unroll
      for (int cf = 0; cf < 2; ++cf) { ach[rf][cf] = zero; acl[rf][cf] = zero; }

    signed char* bc = &smbuf[0][0];      // current (tile t)
    signed char* bn = &smbuf[1][0];      // next (tile t+1)
    signed char* bf = &smbuf[2][0];      // free (target for tile t+2)

    const int nt = K >> 6;
    stage(bc, 0);
    stage(bn, 64);

    for (int t = 0; t < nt; ++t) {
      if (t + 1 < nt) {
        asm volatile("s_waitcnt vmcnt(4)" ::: "memory");   // tile t done, t+1 flies
      } else {
        asm volatile("s_waitcnt vmcnt(0)" ::: "memory");   // last tile: full drain
      }
      __builtin_amdgcn_s_barrier();
      __builtin_amdgcn_sched_barrier(0);
      if (t + 2 < nt) stage(bf, (t + 2) << 6);             // newest 4, fly across barriers

      v4i af[4], bfh[2], bfl[2];
#pragma unroll
      for (int rf = 0; rf < 4; ++rf)
        af[rf] = *(const v4i*)(bc + (wrow + rf * 16 + l15) * 64 + cc);
#pragma unroll
      for (int cf = 0; cf < 2; ++cf) {
        bfh[cf] = *(const v4i*)(bc + HOFF + (wcol + cf * 16 + l15) * 64 + cc);
        bfl[cf] = *(const v4i*)(bc + LOFF + (wcol + cf * 16 + l15) * 64 + cc);
      }
#pragma unroll
      for (int rf = 0; rf < 4; ++rf)
#pragma unroll
        for (int cf = 0; cf < 2; ++cf) {
          ach[rf][cf] = __builtin_amdgcn_mfma_i32_16x16x64_i8(af[rf], bfh[cf], ach[rf][cf], 0, 0, 0);
          acl[rf][cf] = __builtin_amdgcn_mfma_i32_16x16x64_i8(af[rf], bfl[cf], acl[rf][cf], 0, 0, 0);
        }
      signed char* tmp = bc; bc = bn; bn = bf; bf = tmp;   // rotate buffers
    }
    __syncthreads();                     // sub boundary: reads done, safe restage

    // epilogue: float math bit-identical to r5; pack decision bits per r.
    // global weight-col for (cf): c0 + strip*1024 + l15, strip = (wv&1)*2+cf.
#pragma unroll
    for (int cf = 0; cf < 2; ++cf) {
      int strip = (wv & 1) * 2 + cf;
      int col = c0 + strip * 1024 + l15;
      float bqc = bqp[col];
      float nbc = nbp[col];
#pragma unroll
      for (int rf = 0; rf < 4; ++rf)
#pragma unroll
        for (int r = 0; r < 4; ++r) {
          int tot = ach[rf][cf][r] * 256 + acl[rf][cf][r];
          float s = __fmul_rn((float)tot, (1.0f / 6144.0f));
          float s2 = __fadd_rn(__fadd_rn(s, bqc), nbc);
          if (s2 > 0.5f) k12[rf][cf] += ((uint32_t)w << (8 * r));
        }
    }
  }

  // ---- fused tail ----
  // gates LDS: [128 rows][4 strips][16 cols] bytes at smbuf[2]; tables at smbuf[0].
  unsigned char* gates = (unsigned char*)&smbuf[2][0];
  float* Tf  = (float*)&smbuf[0][0];
  float* Ti  = Tf + 256;
  float* Tj  = Ti + 256;
  float* To  = Tj + 256;
  float* Tac = To + 256;

#pragma unroll
  for (int rf = 0; rf < 4; ++rf)
#pragma unroll
    for (int cf = 0; cf < 2; ++cf) {
      int strip = (wv & 1) * 2 + cf;
#pragma unroll
      for (int r = 0; r < 4; ++r) {
        int lrow = wrow + rf * 16 + ((lane >> 4) << 2) + r;
        gates[lrow * 64 + strip * 16 + l15] = (unsigned char)((k12[rf][cf] >> (8 * r)) & 255u);
      }
    }

  const double a1 = (double)a1p[0], a11 = (double)a11p[0];
  const float a3 = a3p[0], a4 = a4p[0], a5 = a5p[0], a6 = a6p[0];
  const float a7 = a7p[0], a8 = a8p[0], a9 = a9p[0], a10 = a10p[0], a11f = a11p[0];
  {
    int pk = tid;
    double s1 = (double)(pk & 15) * (1.0 / 15.0);
    double s2 = (double)(pk >> 4) * (1.0 / 15.0);
    double g = (s1 * (2.0 * a1) - a1) + (s2 * (2.0 * a11) - a11);
    Tf[pk] = quant8(pactf((float)sigd(g), a3), a3);
    Ti[pk] = quant8(pactf((float)sigd(g), a4), a4);
    Tj[pk] = quant8(pactf((float)tanh(g), a5), a5);
    To[pk] = quant8(pactf((float)sigd(g), a6), a6);
    if (tid < 255) {
      float qf = (float)(tid - 127);                       // q in [-127,127]
      float ncv = __fmul_rn(__fdiv_rn(qf, 128.0f), a9);
      Tac[tid] = quant8(pactf((float)tanh((double)ncv), a10), a10);
    }
  }
  __syncthreads();

#pragma unroll
  for (int e = 0; e < 8; ++e) {
    int idx = e * 256 + tid;             // 0..2047
    int lrow = idx >> 4;                 // 0..127
    int hc = idx & 15;
    int grow = row0 + lrow;
    int h = c0 + hc;
    int base = grow * 512 + (h >> 3);
    int sh3 = h & 7;
    int pI = gates[lrow * 64 + 0  + hc] | (((bmb[base]       >> sh3) & 1) << 3);
    int pJ = gates[lrow * 64 + 16 + hc] | (((bmb[base + 128] >> sh3) & 1) << 3);
    int pF = gates[lrow * 64 + 32 + hc] | (((bmb[base + 256] >> sh3) & 1) << 3);
    int pO = gates[lrow * 64 + 48 + hc] | (((bmb[base + 384] >> sh3) & 1) << 3);
    float fg  = Tf[pF];
    float ig  = Ti[pI];
    float act = Tj[pJ];
    float og  = To[pO];
    int oidx = grow * 1024 + h;
    float cxv = cx[oidx];
    float gc  = quant8(pactf(__fmul_rn(cxv, fg), a7), a7);
    float ai  = quant8(pactf(__fmul_rn(ig, act), a8), a8);
    float s   = __fadd_rn(gc, ai);
    float xs  = fminf(fmaxf(__fdiv_rn(pactf(s, a9), a9), -0.9921875f), 0.9921875f);
    float qf  = rintf(__fmul_rn(xs, 128.0f));
    float nc  = __fmul_rn(__fdiv_rn(qf, 128.0f), a9);
    float ac  = Tac[(int)qf + 127];
    float nh  = quant8(pactf(__fmul_rn(ac, og), a11f), a11f);
    out[oidx] = nh;
    out[4194304 + oidx] = nc;
  }
}

// ============================================================================
extern "C" void kernel_launch(void* const* d_in, const int* in_sizes, int n_in,
                              void* d_out, int out_size, void* d_ws, size_t ws_size,
                              hipStream_t stream) {
  const float* input = (const float*)d_in[0];
  const float* hx    = (const float*)d_in[1];
  const float* cx    = (const float*)d_in[2];
  const float* wih   = (const float*)d_in[3];
  const float* whh   = (const float*)d_in[4];
  const float* bih   = (const float*)d_in[5];
  const float* bhh   = (const float*)d_in[6];
  const float* a1p   = (const float*)d_in[7];
  const float* a3p   = (const float*)d_in[8];
  const float* a4p   = (const float*)d_in[9];
  const float* a5p   = (const float*)d_in[10];
  const float* a6p   = (const float*)d_in[11];
  const float* a7p   = (const float*)d_in[12];
  const float* a8p   = (const float*)d_in[13];
  const float* a9p   = (const float*)d_in[14];
  const float* a10p  = (const float*)d_in[15];
  const float* a11p  = (const float*)d_in[16];

  char* ws = (char*)d_ws;
  unsigned* enc        = (unsigned*)ws;                            // 256 B
  float* T0            = (float*)(ws + 256);                       // 4 MiB  [256][4096]
  float* bq_ih         = (float*)(ws + 256 + 4194304);             // 64 KiB x4
  float* nb_ih         = bq_ih + 16384;
  float* bq_hh         = nb_ih + 16384;
  float* nb_hh         = bq_hh + 16384;
  unsigned char* kv_ih = (unsigned char*)(nb_hh + 16384);          // 1 MiB [256][4096]
  signed char* A_hh    = (signed char*)(kv_ih + 1048576);          // 16 MiB [4][4096][1024]
  signed char* Bt_hh   = A_hh + 16777216;                          // 32 MiB [2][4][4096][1024]
  signed char* A_ih    = Bt_hh + 33554432;                         // 3 MiB [3][4096][256]
  signed char* Bt_ih   = A_ih + 3145728;                           // 6 MiB [2][3][4096][256]
  unsigned* bm         = (unsigned*)(Bt_ih + 6291456);             // 2 MiB [4096][128]
  // total ~64.3 MiB

  hipMemsetAsync(enc, 0, 64, stream);

  rmax_all_kernel<<<1152, 256, 0, stream>>>(wih, whh, bih, bhh, enc);

  prep_all_kernel<<<29824, 256, 0, stream>>>(input, hx, wih, whh, bih, bhh, a1p, a11p,
                                             enc, kv_ih, A_ih, A_hh, bq_ih, nb_ih,
                                             bq_hh, nb_hh, T0, Bt_hh, Bt_ih);

  gemm_p0_kernel<<<dim3(128, 16), 256, 0, stream>>>(T0, bq_ih, nb_ih, kv_ih, bm);

  gemm_mfma_tail_kernel<<<dim3(64, 32), 256, 0, stream>>>(
      A_hh, Bt_hh, A_ih, Bt_ih, bq_hh, nb_hh, bq_ih, nb_ih,
      (const unsigned char*)bm, cx,
      a1p, a3p, a4p, a5p, a6p, a7p, a8p, a9p, a10p, a11p, (float*)d_out);
}